// Round 2
// baseline (352.446 us; speedup 1.0000x reference)
//
#include <hip/hip_runtime.h>
#include <hip/hip_bf16.h>
#include <math.h>

#define N_FRAMES 100000
#define HIDDEN 512
#define N_QUERIES 256
#define N_EVENTS 2048
#define TOPK 8
#define FRAME_RATE 5.0f
#define EPSN 1e-12f

// ---------------- ws layout (bytes) ----------------
// avg     : [2048][512] f32   @ 0          (4 MB)
// ts      : [2048][2]   f32   @ 4194304
// inv_en  : [2048]      f32   @ 4210688
// inv_qn  : [256]       f32   @ 4218880
// start   : [2048]      i32   @ 4219904
// end     : [2048]      i32   @ 4228096
// sim     : [256][2048] f32   @ 4236288    (2 MB)

// blocks 0..255: per-query inv-norm (one wave each)
// blocks 256..287: init start/end = -1 (64 events per block)
__global__ void initq_k(const float* __restrict__ qf, float* __restrict__ inv_qn,
                        int* __restrict__ start, int* __restrict__ end) {
    int blk = blockIdx.x;
    int lane = threadIdx.x;  // 64
    if (blk < N_QUERIES) {
        const float* row = qf + (size_t)blk * HIDDEN;
        float ss = 0.f;
        #pragma unroll
        for (int i = 0; i < 8; ++i) { float v = row[lane + 64 * i]; ss += v * v; }
        #pragma unroll
        for (int off = 32; off; off >>= 1) ss += __shfl_xor(ss, off);
        if (lane == 0) inv_qn[blk] = 1.0f / fmaxf(sqrtf(ss), EPSN);
    } else {
        int e = (blk - N_QUERIES) * 64 + lane;
        start[e] = -1; end[e] = -1;
    }
}

__global__ void bounds_k(const int* __restrict__ ev, int* __restrict__ start,
                         int* __restrict__ end) {
    int i = blockIdx.x * blockDim.x + threadIdx.x;
    if (i >= N_FRAMES) return;
    int e = ev[i];
    if (i == 0 || ev[i - 1] != e) start[e] = i;
    if (i == N_FRAMES - 1 || ev[i + 1] != e) end[e] = i;
}

// one block (256 threads) per event; halves take alternating frames (stride 2)
__global__ void pool_k(const float* __restrict__ vf, const int* __restrict__ start,
                       const int* __restrict__ end, float* __restrict__ avg,
                       float* __restrict__ inv_en, float* __restrict__ ts) {
    int e = blockIdx.x;
    int s = start[e], t = end[e];
    int tid = threadIdx.x;
    int half = tid >> 7;
    int l = tid & 127;
    float4 acc = make_float4(0.f, 0.f, 0.f, 0.f);
    if (s >= 0) {
        const float4* p = (const float4*)vf + (size_t)(s + half) * 128 + l;
        int f = s + half;
        for (; f + 2 <= t; f += 4, p += 512) {
            float4 v0 = p[0];
            float4 v1 = p[256];
            acc.x += v0.x + v1.x; acc.y += v0.y + v1.y;
            acc.z += v0.z + v1.z; acc.w += v0.w + v1.w;
        }
        if (f <= t) {
            float4 v0 = *p;
            acc.x += v0.x; acc.y += v0.y; acc.z += v0.z; acc.w += v0.w;
        }
    }
    __shared__ float4 buf[128];
    __shared__ float ssbuf[2];
    if (half) buf[l] = acc;
    __syncthreads();
    if (!half) {
        float4 o = buf[l];
        acc.x += o.x; acc.y += o.y; acc.z += o.z; acc.w += o.w;
        if (s >= 0) {
            float cnt = (float)(t - s + 1);
            acc.x /= cnt; acc.y /= cnt; acc.z /= cnt; acc.w /= cnt;
        }
        *((float4*)avg + (size_t)e * 128 + l) = acc;
        float ss = acc.x * acc.x + acc.y * acc.y + acc.z * acc.z + acc.w * acc.w;
        #pragma unroll
        for (int off = 32; off; off >>= 1) ss += __shfl_xor(ss, off);
        if ((tid & 63) == 0) ssbuf[tid >> 6] = ss;
    }
    __syncthreads();
    if (tid == 0) {
        float ss = ssbuf[0] + ssbuf[1];
        inv_en[e] = (s >= 0) ? 1.0f / fmaxf(sqrtf(ss), EPSN) : 0.0f;
        ts[e * 2 + 0] = (s >= 0) ? (float)s / FRAME_RATE : 0.0f;
        ts[e * 2 + 1] = (s >= 0) ? (float)t / FRAME_RATE : 0.0f;
    }
}

// sim tile: BQ=64 x BE=32 per block; 128 threads, micro-tile 4q x 4e.
// 8 ds_read_b128 -> 64 FMA per 4-d step (2x the intensity of the 4qx2e version).
// Bank audit (DCP=132, 132%32=4): e-rows e0+8j -> banks 4*e0+d (e0=0..7 covers all
// 32 banks, conflict-free); q-rows q0+16i -> banks 4*(q0&7)+d likewise.
#define BQ 64
#define BE 32
#define DC 128
#define DCP 132

__global__ void sim_k(const float* __restrict__ qf, const float* __restrict__ avg,
                      const float* __restrict__ inv_qn, const float* __restrict__ inv_en,
                      float* __restrict__ sim) {
    __shared__ float qs[BQ][DCP];
    __shared__ float es[BE][DCP];
    int tid = threadIdx.x;         // 0..127
    int qbase = blockIdx.y * BQ;
    int ebase = blockIdx.x * BE;
    int q0 = tid >> 3;             // 16 groups, queries q0 + 16*i
    int e0 = tid & 7;              // 8 groups,  events  e0 + 8*j
    float acc[4][4] = {{0.f,0.f,0.f,0.f},{0.f,0.f,0.f,0.f},
                       {0.f,0.f,0.f,0.f},{0.f,0.f,0.f,0.f}};
    for (int dc = 0; dc < HIDDEN; dc += DC) {
        __syncthreads();
        #pragma unroll
        for (int r = 0; r < 16; ++r) {   // 64x128 f32 = 2048 f4 / 128 thr
            int ldx = tid + 128 * r;
            int row = ldx >> 5, c4 = ldx & 31;
            *(float4*)&qs[row][c4 * 4] =
                *(const float4*)(qf + (size_t)(qbase + row) * HIDDEN + dc + c4 * 4);
        }
        #pragma unroll
        for (int r = 0; r < 8; ++r) {    // 32x128 f32 = 1024 f4 / 128 thr
            int ldx = tid + 128 * r;
            int row = ldx >> 5, c4 = ldx & 31;
            *(float4*)&es[row][c4 * 4] =
                *(const float4*)(avg + (size_t)(ebase + row) * HIDDEN + dc + c4 * 4);
        }
        __syncthreads();
        #pragma unroll 2
        for (int d = 0; d < DC; d += 4) {
            float4 ev0 = *(const float4*)&es[e0][d];
            float4 ev1 = *(const float4*)&es[e0 + 8][d];
            float4 ev2 = *(const float4*)&es[e0 + 16][d];
            float4 ev3 = *(const float4*)&es[e0 + 24][d];
            #pragma unroll
            for (int i = 0; i < 4; ++i) {
                float4 qv = *(const float4*)&qs[q0 + 16 * i][d];
                acc[i][0] += qv.x * ev0.x + qv.y * ev0.y + qv.z * ev0.z + qv.w * ev0.w;
                acc[i][1] += qv.x * ev1.x + qv.y * ev1.y + qv.z * ev1.z + qv.w * ev1.w;
                acc[i][2] += qv.x * ev2.x + qv.y * ev2.y + qv.z * ev2.z + qv.w * ev2.w;
                acc[i][3] += qv.x * ev3.x + qv.y * ev3.y + qv.z * ev3.z + qv.w * ev3.w;
            }
        }
    }
    float iq[4], ie[4];
    #pragma unroll
    for (int i = 0; i < 4; ++i) iq[i] = inv_qn[qbase + q0 + 16 * i];
    #pragma unroll
    for (int j = 0; j < 4; ++j) ie[j] = inv_en[ebase + e0 + 8 * j];
    #pragma unroll
    for (int i = 0; i < 4; ++i) {
        size_t rowoff = (size_t)(qbase + q0 + 16 * i) * N_EVENTS + ebase;
        #pragma unroll
        for (int j = 0; j < 4; ++j)
            sim[rowoff + e0 + 8 * j] = acc[i][j] * iq[i] * ie[j];
    }
}

// one wave per query: top-8 (lower-index tie-break, matching jax.lax.top_k)
// then the bbox regression for the 8 chosen events — no top_idx round-trip.
__global__ void topk_final_k(const float* __restrict__ sim, const float* __restrict__ ts,
                             const float* __restrict__ avg, const float* __restrict__ qf,
                             const float* __restrict__ W, const float* __restrict__ b,
                             float* __restrict__ out) {
    int q = blockIdx.x;
    int lane = threadIdx.x;  // 64
    const float4* row4 = (const float4*)(sim + (size_t)q * N_EVENTS);
    float4 v4[8];
    #pragma unroll
    for (int g = 0; g < 8; ++g) v4[g] = row4[lane + 64 * g];
    int chosen[TOPK];
    #pragma unroll
    for (int k = 0; k < TOPK; ++k) {
        float best = -INFINITY;
        int bidx = 0x7fffffff;
        #pragma unroll
        for (int g = 0; g < 8; ++g) {     // per-lane scan in ascending idx order
            #pragma unroll
            for (int j = 0; j < 4; ++j) {
                int idx = 4 * lane + 256 * g + j;
                float val = (j == 0) ? v4[g].x : (j == 1) ? v4[g].y
                          : (j == 2) ? v4[g].z : v4[g].w;
                bool dup = false;
                #pragma unroll
                for (int m = 0; m < TOPK; ++m)
                    dup = dup || ((m < k) && (chosen[m] == idx));
                if (!dup && val > best) { best = val; bidx = idx; }
            }
        }
        #pragma unroll
        for (int off = 32; off; off >>= 1) {
            float ov = __shfl_xor(best, off);
            int oi = __shfl_xor(bidx, off);
            if (ov > best || (ov == best && oi < bidx)) { best = ov; bidx = oi; }
        }
        chosen[k] = bidx;   // k compile-time -> stays in registers
    }
    const float* qrow = qf + (size_t)q * HIDDEN;
    float qreg[8];
    float2 wreg[8];
    #pragma unroll
    for (int i = 0; i < 8; ++i) qreg[i] = qrow[lane + 64 * i];
    #pragma unroll
    for (int i = 0; i < 8; ++i) wreg[i] = ((const float2*)W)[lane + 64 * i];
    float b0s = b[0], b1s = b[1];
    #pragma unroll
    for (int k = 0; k < TOPK; ++k) {
        int e = chosen[k];
        const float* frow = avg + (size_t)e * HIDDEN;
        float a0 = 0.f, a1 = 0.f;
        #pragma unroll
        for (int i = 0; i < 8; ++i) {
            float f = frow[lane + 64 * i] * qreg[i];
            a0 += f * wreg[i].x;
            a1 += f * wreg[i].y;
        }
        #pragma unroll
        for (int off = 32; off; off >>= 1) {
            a0 += __shfl_xor(a0, off);
            a1 += __shfl_xor(a1, off);
        }
        if (lane == 0) {
            float t0 = ts[e * 2 + 0], t1 = ts[e * 2 + 1];
            float dur = t1 - t0;
            out[(q * TOPK + k) * 2 + 0] = t0 + tanhf(a0 + b0s) * dur;
            out[(q * TOPK + k) * 2 + 1] = t1 + tanhf(a1 + b1s) * dur;
        }
    }
}

extern "C" void kernel_launch(void* const* d_in, const int* in_sizes, int n_in,
                              void* d_out, int out_size, void* d_ws, size_t ws_size,
                              hipStream_t stream) {
    const float* vf = (const float*)d_in[0];      // [1,100000,512]
    const float* qf = (const float*)d_in[1];      // [256,512]
    const int* ev = (const int*)d_in[2];          // [100000]
    const float* W = (const float*)d_in[3];       // [512,2]
    const float* b = (const float*)d_in[4];       // [2]
    float* out = (float*)d_out;

    char* ws = (char*)d_ws;
    float* avg    = (float*)(ws + 0);
    float* ts     = (float*)(ws + 4194304);
    float* inv_en = (float*)(ws + 4210688);
    float* inv_qn = (float*)(ws + 4218880);
    int*   start  = (int*)  (ws + 4219904);
    int*   endp   = (int*)  (ws + 4228096);
    float* sim    = (float*)(ws + 4236288);

    initq_k<<<N_QUERIES + N_EVENTS / 64, 64, 0, stream>>>(qf, inv_qn, start, endp);
    bounds_k<<<(N_FRAMES + 255) / 256, 256, 0, stream>>>(ev, start, endp);
    pool_k<<<N_EVENTS, 256, 0, stream>>>(vf, start, endp, avg, inv_en, ts);
    dim3 sgrid(N_EVENTS / BE, N_QUERIES / BQ);
    sim_k<<<sgrid, 128, 0, stream>>>(qf, avg, inv_qn, inv_en, sim);
    topk_final_k<<<N_QUERIES, 64, 0, stream>>>(sim, ts, avg, qf, W, b, out);
}

// Round 4
// 340.360 us; speedup vs baseline: 1.0355x; 1.0355x over previous
//
#include <hip/hip_runtime.h>
#include <hip/hip_bf16.h>
#include <math.h>

#define N_FRAMES 100000
#define HIDDEN 512
#define N_QUERIES 256
#define N_EVENTS 2048
#define TOPK 8
#define FRAME_RATE 5.0f
#define EPSN 1e-12f

// ---------------- ws layout (bytes) ----------------
// avg     : [2048][512] f32   @ 0          (4 MB)
// ts      : [2048][2]   f32   @ 4194304
// inv_en  : [2048]      f32   @ 4210688
// inv_qn  : [256]       f32   @ 4218880
// start   : [2048]      i32   @ 4219904
// end     : [2048]      i32   @ 4228096
// part    : [2][256][2048] f32 @ 4236288   (4 MB; split-K partial dots)

// blocks 0..255: per-query inv-norm (one wave each)
// blocks 256..287: init start/end = -1 (64 events per block)
__global__ void initq_k(const float* __restrict__ qf, float* __restrict__ inv_qn,
                        int* __restrict__ start, int* __restrict__ end) {
    int blk = blockIdx.x;
    int lane = threadIdx.x;  // 64
    if (blk < N_QUERIES) {
        const float* row = qf + (size_t)blk * HIDDEN;
        float ss = 0.f;
        #pragma unroll
        for (int i = 0; i < 8; ++i) { float v = row[lane + 64 * i]; ss += v * v; }
        #pragma unroll
        for (int off = 32; off; off >>= 1) ss += __shfl_xor(ss, off);
        if (lane == 0) inv_qn[blk] = 1.0f / fmaxf(sqrtf(ss), EPSN);
    } else {
        int e = (blk - N_QUERIES) * 64 + lane;
        start[e] = -1; end[e] = -1;
    }
}

__global__ void bounds_k(const int* __restrict__ ev, int* __restrict__ start,
                         int* __restrict__ end) {
    int i = blockIdx.x * blockDim.x + threadIdx.x;
    if (i >= N_FRAMES) return;
    int e = ev[i];
    if (i == 0 || ev[i - 1] != e) start[e] = i;
    if (i == N_FRAMES - 1 || ev[i + 1] != e) end[e] = i;
}

// one block (256 threads) per event; halves take alternating frames (stride 2)
__global__ void pool_k(const float* __restrict__ vf, const int* __restrict__ start,
                       const int* __restrict__ end, float* __restrict__ avg,
                       float* __restrict__ inv_en, float* __restrict__ ts) {
    int e = blockIdx.x;
    int s = start[e], t = end[e];
    int tid = threadIdx.x;
    int half = tid >> 7;
    int l = tid & 127;
    float4 acc = make_float4(0.f, 0.f, 0.f, 0.f);
    if (s >= 0) {
        const float4* p = (const float4*)vf + (size_t)(s + half) * 128 + l;
        int f = s + half;
        for (; f + 2 <= t; f += 4, p += 512) {
            float4 v0 = p[0];
            float4 v1 = p[256];
            acc.x += v0.x + v1.x; acc.y += v0.y + v1.y;
            acc.z += v0.z + v1.z; acc.w += v0.w + v1.w;
        }
        if (f <= t) {
            float4 v0 = *p;
            acc.x += v0.x; acc.y += v0.y; acc.z += v0.z; acc.w += v0.w;
        }
    }
    __shared__ float4 buf[128];
    __shared__ float ssbuf[2];
    if (half) buf[l] = acc;
    __syncthreads();
    if (!half) {
        float4 o = buf[l];
        acc.x += o.x; acc.y += o.y; acc.z += o.z; acc.w += o.w;
        if (s >= 0) {
            float cnt = (float)(t - s + 1);
            acc.x /= cnt; acc.y /= cnt; acc.z /= cnt; acc.w /= cnt;
        }
        *((float4*)avg + (size_t)e * 128 + l) = acc;
        float ss = acc.x * acc.x + acc.y * acc.y + acc.z * acc.z + acc.w * acc.w;
        #pragma unroll
        for (int off = 32; off; off >>= 1) ss += __shfl_xor(ss, off);
        if ((tid & 63) == 0) ssbuf[tid >> 6] = ss;
    }
    __syncthreads();
    if (tid == 0) {
        float ss = ssbuf[0] + ssbuf[1];
        inv_en[e] = (s >= 0) ? 1.0f / fmaxf(sqrtf(ss), EPSN) : 0.0f;
        ts[e * 2 + 0] = (s >= 0) ? (float)s / FRAME_RATE : 0.0f;
        ts[e * 2 + 1] = (s >= 0) ? (float)t / FRAME_RATE : 0.0f;
    }
}

// sim partial-dot: BQ=64 x BE=32 tile, 128 threads, micro-tile 4q x 4e,
// split-K=2 over blockIdx.z (each block does 256 of 512 dims).
// grid = 64 x 4 x 2 = 512 blocks -> 2 blocks/CU, 4 waves/CU (vs R2's 2).
// LDS: qs 33.8K + es 16.9K = 50.7 KB/block; 2/CU = 101 KB (fits 160).
// Bank audit (DCP=132): e-rows e0+8j and q-rows q0+16i land on disjoint
// bank quads across the 8/16 groups -> conflict-free ds_read_b128.
#define BQ 64
#define BE 32
#define DC 128
#define DCP 132
#define KSPLIT 2
#define KHALF (HIDDEN / KSPLIT)

__global__ void sim_k(const float* __restrict__ qf, const float* __restrict__ avg,
                      float* __restrict__ part) {
    __shared__ float qs[BQ][DCP];
    __shared__ float es[BE][DCP];
    int tid = threadIdx.x;         // 0..127
    int qbase = blockIdx.y * BQ;
    int ebase = blockIdx.x * BE;
    int kb = blockIdx.z;           // 0 or 1
    int q0 = tid >> 3;             // 16 groups, queries q0 + 16*i
    int e0 = tid & 7;              // 8 groups,  events  e0 + 8*j
    float acc[4][4] = {{0.f,0.f,0.f,0.f},{0.f,0.f,0.f,0.f},
                       {0.f,0.f,0.f,0.f},{0.f,0.f,0.f,0.f}};
    for (int dcl = 0; dcl < KHALF; dcl += DC) {
        int dc = kb * KHALF + dcl;
        __syncthreads();
        #pragma unroll
        for (int r = 0; r < 16; ++r) {   // 64x128 f32 = 2048 f4 / 128 thr
            int ldx = tid + 128 * r;
            int row = ldx >> 5, c4 = ldx & 31;
            *(float4*)&qs[row][c4 * 4] =
                *(const float4*)(qf + (size_t)(qbase + row) * HIDDEN + dc + c4 * 4);
        }
        #pragma unroll
        for (int r = 0; r < 8; ++r) {    // 32x128 f32 = 1024 f4 / 128 thr
            int ldx = tid + 128 * r;
            int row = ldx >> 5, c4 = ldx & 31;
            *(float4*)&es[row][c4 * 4] =
                *(const float4*)(avg + (size_t)(ebase + row) * HIDDEN + dc + c4 * 4);
        }
        __syncthreads();
        #pragma unroll 2
        for (int d = 0; d < DC; d += 4) {
            float4 ev0 = *(const float4*)&es[e0][d];
            float4 ev1 = *(const float4*)&es[e0 + 8][d];
            float4 ev2 = *(const float4*)&es[e0 + 16][d];
            float4 ev3 = *(const float4*)&es[e0 + 24][d];
            #pragma unroll
            for (int i = 0; i < 4; ++i) {
                float4 qv = *(const float4*)&qs[q0 + 16 * i][d];
                acc[i][0] += qv.x * ev0.x + qv.y * ev0.y + qv.z * ev0.z + qv.w * ev0.w;
                acc[i][1] += qv.x * ev1.x + qv.y * ev1.y + qv.z * ev1.z + qv.w * ev1.w;
                acc[i][2] += qv.x * ev2.x + qv.y * ev2.y + qv.z * ev2.z + qv.w * ev2.w;
                acc[i][3] += qv.x * ev3.x + qv.y * ev3.y + qv.z * ev3.z + qv.w * ev3.w;
            }
        }
    }
    float* pk = part + (size_t)kb * N_QUERIES * N_EVENTS;
    #pragma unroll
    for (int i = 0; i < 4; ++i) {
        size_t rowoff = (size_t)(qbase + q0 + 16 * i) * N_EVENTS + ebase;
        #pragma unroll
        for (int j = 0; j < 4; ++j)
            pk[rowoff + e0 + 8 * j] = acc[i][j];
    }
}

// one wave per query: sum split-K partials + normalize on the fly, top-8
// (lower-index tie-break, matching jax.lax.top_k), then bbox regression.
__global__ void topk_final_k(const float* __restrict__ part, const float* __restrict__ inv_en,
                             const float* __restrict__ inv_qn, const float* __restrict__ ts,
                             const float* __restrict__ avg, const float* __restrict__ qf,
                             const float* __restrict__ W, const float* __restrict__ b,
                             float* __restrict__ out) {
    int q = blockIdx.x;
    int lane = threadIdx.x;  // 64
    const float4* r0 = (const float4*)(part + (size_t)q * N_EVENTS);
    const float4* r1 = (const float4*)(part + (size_t)N_QUERIES * N_EVENTS + (size_t)q * N_EVENTS);
    const float4* ie4 = (const float4*)inv_en;
    float iq = inv_qn[q];
    float4 v4[8];
    #pragma unroll
    for (int g = 0; g < 8; ++g) {
        float4 a = r0[lane + 64 * g];
        float4 c = r1[lane + 64 * g];
        float4 e = ie4[lane + 64 * g];
        v4[g].x = (a.x + c.x) * e.x * iq;
        v4[g].y = (a.y + c.y) * e.y * iq;
        v4[g].z = (a.z + c.z) * e.z * iq;
        v4[g].w = (a.w + c.w) * e.w * iq;
    }
    int chosen[TOPK];
    #pragma unroll
    for (int k = 0; k < TOPK; ++k) {
        float best = -INFINITY;
        int bidx = 0x7fffffff;
        #pragma unroll
        for (int g = 0; g < 8; ++g) {     // ascending idx scan per lane
            #pragma unroll
            for (int j = 0; j < 4; ++j) {
                int idx = 4 * lane + 256 * g + j;
                float val = (j == 0) ? v4[g].x : (j == 1) ? v4[g].y
                          : (j == 2) ? v4[g].z : v4[g].w;
                bool dup = false;
                #pragma unroll
                for (int m = 0; m < TOPK; ++m)
                    dup = dup || ((m < k) && (chosen[m] == idx));
                if (!dup && val > best) { best = val; bidx = idx; }
            }
        }
        #pragma unroll
        for (int off = 32; off; off >>= 1) {
            float ov = __shfl_xor(best, off);
            int oi = __shfl_xor(bidx, off);
            if (ov > best || (ov == best && oi < bidx)) { best = ov; bidx = oi; }
        }
        chosen[k] = bidx;   // k compile-time -> stays in registers
    }
    const float* qrow = qf + (size_t)q * HIDDEN;
    float qreg[8];
    float2 wreg[8];
    #pragma unroll
    for (int i = 0; i < 8; ++i) qreg[i] = qrow[lane + 64 * i];
    #pragma unroll
    for (int i = 0; i < 8; ++i) wreg[i] = ((const float2*)W)[lane + 64 * i];
    float b0s = b[0], b1s = b[1];
    #pragma unroll
    for (int k = 0; k < TOPK; ++k) {
        int e = chosen[k];
        const float* frow = avg + (size_t)e * HIDDEN;
        float a0 = 0.f, a1 = 0.f;
        #pragma unroll
        for (int i = 0; i < 8; ++i) {
            float f = frow[lane + 64 * i] * qreg[i];
            a0 += f * wreg[i].x;
            a1 += f * wreg[i].y;
        }
        #pragma unroll
        for (int off = 32; off; off >>= 1) {
            a0 += __shfl_xor(a0, off);
            a1 += __shfl_xor(a1, off);
        }
        if (lane == 0) {
            float t0 = ts[e * 2 + 0], t1 = ts[e * 2 + 1];
            float dur = t1 - t0;
            out[(q * TOPK + k) * 2 + 0] = t0 + tanhf(a0 + b0s) * dur;
            out[(q * TOPK + k) * 2 + 1] = t1 + tanhf(a1 + b1s) * dur;
        }
    }
}

extern "C" void kernel_launch(void* const* d_in, const int* in_sizes, int n_in,
                              void* d_out, int out_size, void* d_ws, size_t ws_size,
                              hipStream_t stream) {
    const float* vf = (const float*)d_in[0];      // [1,100000,512]
    const float* qf = (const float*)d_in[1];      // [256,512]
    const int* ev = (const int*)d_in[2];          // [100000]
    const float* W = (const float*)d_in[3];       // [512,2]
    const float* b = (const float*)d_in[4];       // [2]
    float* out = (float*)d_out;

    char* ws = (char*)d_ws;
    float* avg    = (float*)(ws + 0);
    float* ts     = (float*)(ws + 4194304);
    float* inv_en = (float*)(ws + 4210688);
    float* inv_qn = (float*)(ws + 4218880);
    int*   start  = (int*)  (ws + 4219904);
    int*   endp   = (int*)  (ws + 4228096);
    float* part   = (float*)(ws + 4236288);

    initq_k<<<N_QUERIES + N_EVENTS / 64, 64, 0, stream>>>(qf, inv_qn, start, endp);
    bounds_k<<<(N_FRAMES + 255) / 256, 256, 0, stream>>>(ev, start, endp);
    pool_k<<<N_EVENTS, 256, 0, stream>>>(vf, start, endp, avg, inv_en, ts);
    dim3 sgrid(N_EVENTS / BE, N_QUERIES / BQ, KSPLIT);
    sim_k<<<sgrid, 128, 0, stream>>>(qf, avg, part);
    topk_final_k<<<N_QUERIES, 64, 0, stream>>>(part, inv_en, inv_qn, ts, avg, qf, W, b, out);
}